// Round 1
// baseline (181.494 us; speedup 1.0000x reference)
//
#include <hip/hip_runtime.h>

// MeshTokenizer: B=64, NV=8192, NF=16384.
// Outputs concatenated flat as float32:
//   [0] input_ids        64 x 163841   @ 0
//   [1] attention_mask   64 x 163841   @ 10485824   (all ones == full region)
//   [2] codes            64x16384x3x3  @ 20971648
//   [3] discrete_face_coords (==codes) @ 30408832
//   [4] recon_faces      64x1x3x3      @ 39846016
// 159.4 MB writes + ~20 MB reads -> ~28 us write-roofline @6.3 TB/s.
//
// R7 theory: timed window = harness poison fill (~94us, fixed) + ours (~85us).
// mesh_tok was ~83us = 3x its roofline; the fill kernel proves plain streaming
// stores reach 6.7 TB/s, so the gap is structural:
//  - __syncthreads() per block forced a vmcnt(0)+lgkmcnt(0) drain between the
//    gather/mask phase and the ids/codes store phase -> bursty store issue.
//    FIX: per-wave LDS slices (s_ids[4][644], s_codes[4][576]); each wave
//    stages and reads back ONLY its own 64 faces. Wave-local ds ordering via
//    compiler lgkmcnt -> NO barrier in the kernel at all.
//  - attention_mask (41.9 MB, 26% of writes) is input-independent and is
//    exactly the full region [OFF_MASK, OFF_C1) -> moved to pass A as a pure
//    grid-stride vf4 stream (fill-rate, ~6.6us).
//  - unpack via (float)((pk>>8i)&0xff) -> v_cvt_f32_ubyte{0,1,2}, 1 VALU each.

#define B_      64
#define NV_     8192
#define NF_     16384
#define ROW_    (NF_ * 10 + 1)   // 163841 (odd stride -> per-batch dword phase b&3)
#define OFF_IDS   ((size_t)0)
#define OFF_MASK  ((size_t)10485824)
#define OFF_C1    ((size_t)20971648)
#define OFF_C2    ((size_t)30408832)
#define OFF_REC   ((size_t)39846016)
#define MASK_VF4  2621456u        // 10,485,824 floats / 4

typedef float vf4 __attribute__((ext_vector_type(4)));

__device__ __forceinline__ float disc1(float x) {
    // (x-LO)/(HI-LO)*128 - 0.5 == (x+1)*64 - 0.5 bit-exactly; round-half-even
    float r = rintf((x + 1.0f) * 64.0f - 0.5f);
    return fminf(fmaxf(r, 0.0f), 127.0f);
}

// ---- Pass A: per-vertex discretize+pack (64*8192 = 524288 verts) + mask fill.
// Mask is the entire [OFF_MASK, OFF_C1) region = memset(1.0f): pure stream.
__global__ __launch_bounds__(256) void pack_verts_kernel(
        const float* __restrict__ verts,
        unsigned int* __restrict__ packed,
        float*        __restrict__ out) {
    const int g = blockIdx.x * 256 + threadIdx.x;      // 0..524287
    const float* vp = verts + (size_t)g * 3;
    const unsigned int c0 = (unsigned int)disc1(vp[0]);
    const unsigned int c1 = (unsigned int)disc1(vp[1]);
    const unsigned int c2 = (unsigned int)disc1(vp[2]);
    packed[g] = c0 | (c1 << 8) | (c2 << 16);

    const vf4 ones = {1.0f, 1.0f, 1.0f, 1.0f};
    vf4* m4 = (vf4*)(out + OFF_MASK);
    for (unsigned int f4 = (unsigned int)g; f4 < MASK_VF4; f4 += 524288u)
        m4[f4] = ones;
}

// ---- Pass B: one block = 256 consecutive faces of one batch; wave w owns
// faces [j0+64w, j0+64w+64) and global ids span [Sw, Sw+640), Sw = S + 640w
// (640w % 4 == 0 -> same dword phase p = S&3 for every wave). Each wave
// stages into its OWN LDS slice and reads back only its own slice ->
// no __syncthreads, no vmcnt-drain; stores stream continuously.
// Per wave: head pp scalar + nf4 aligned vf4 + tail p scalar = 640 words.
__global__ __launch_bounds__(256) void mesh_tok_kernel(
        const unsigned int* __restrict__ packed,
        const int*          __restrict__ faces,
        float*              __restrict__ out) {
    const int t   = threadIdx.x;
    const int w   = t >> 6;              // wave 0..3
    const int l   = t & 63;              // lane
    const int blk = blockIdx.x;
    const int b   = blk >> 6;            // batch
    const int j0  = (blk & 63) << 8;     // first face of this block
    const int j   = j0 + (w << 6) + l;   // face this thread owns

    __shared__ __align__(16) float s_ids[4][644];    // 2576 B/slice, 16B-aligned
    __shared__ __align__(16) float s_codes[4][576];  // 2304 B/slice, 16B-aligned

    const size_t S   = (size_t)b * ROW_ + (size_t)j0 * 10;
    const int    p   = (int)(S & 3);                 // == b & 3
    const int    pp  = (4 - p) & 3;
    const size_t Sw  = S + (size_t)(w * 640);        // this wave's span start
    const size_t Aw  = Sw + (size_t)pp;              // 16B-aligned start
    const int    nf4 = (p == 0) ? 160 : 159;
    const int    lb  = (p == 0) ? 0 : 1;             // (p+pp)/4

    // ---- issue gather loads (face idx -> packed codes) ----
    const int* fp = faces + ((size_t)b * NF_ + j) * 3;
    const unsigned int* pb = packed + (size_t)b * NV_;
    const int i0 = fp[0], i1 = fp[1], i2 = fp[2];
    const unsigned int pk0 = pb[i0], pk1 = pb[i1], pk2 = pb[i2];

    // ---- unpack: fields are byte-aligned & <128, so &0xff == &127 and
    // hipcc pattern-matches to v_cvt_f32_ubyte{0,1,2} ----
    float code_f[9];
    const unsigned int pk[3] = {pk0, pk1, pk2};
    #pragma unroll
    for (int vi = 0; vi < 3; ++vi) {
        code_f[vi * 3 + 0] = (float)(pk[vi] & 0xffu);
        code_f[vi * 3 + 1] = (float)((pk[vi] >> 8) & 0xffu);
        code_f[vi * 3 + 2] = (float)((pk[vi] >> 16) & 0xffu);
    }

    // ---- wave-local staging (phase-shifted); slice words p .. p+639 ----
    s_ids[w][p + l * 10] = (j == 0) ? -1.0f : 128.0f;   // sep of j-1 / lead pad
    #pragma unroll
    for (int k = 0; k < 9; ++k) {
        s_ids[w][p + l * 10 + 1 + k] = code_f[k];
        s_codes[w][l * 9 + k]        = code_f[k];
    }
    // NO __syncthreads(): readers below touch only this wave's slice; the
    // ds_write -> ds_read dependency is enforced by lgkmcnt within the wave.

    float* out_ids = out + OFF_IDS;

    // ---- ids: head scalars + aligned vf4 body + tail scalars, all per-wave ----
    {
        const vf4* s4   = (const vf4*)&s_ids[w][0];
        vf4*       ids4 = (vf4*)(out_ids + Aw);
        for (int f4 = l; f4 < nf4; f4 += 64) ids4[f4] = s4[lb + f4];
        if (l < pp)              out_ids[Sw + l] = s_ids[w][p + l];
        if (l >= 4 && l < 4 + p) out_ids[Sw + 640 - p + (l - 4)] = s_ids[w][640 + (l - 4)];
    }

    // ---- codes x2: naturally 16B-aligned, per-wave 144 vf4 ----
    {
        const size_t baseC = ((size_t)b * NF_ + (size_t)(j0 + (w << 6))) * 9;
        const vf4* sc4 = (const vf4*)&s_codes[w][0];
        vf4* c1p = (vf4*)(out + OFF_C1 + baseC);
        vf4* c2p = (vf4*)(out + OFF_C2 + baseC);
        for (int f4 = l; f4 < 144; f4 += 64) {
            vf4 v = sc4[f4];
            c1p[f4] = v;
            c2p[f4] = v;
        }
    }

    // ---- final ids pad + recon_faces (thread 0 of block holds face j0) ----
    if (t == 0) {
        if (j0 == NF_ - 256)
            out_ids[(size_t)b * ROW_ + (ROW_ - 1)] = -1.0f;
        if (j0 == 0) {  // face 0 of batch b
            float* out_rec = out + OFF_REC;
            #pragma unroll
            for (int k = 0; k < 9; ++k)
                out_rec[b * 9 + k] = (code_f[k] + 0.5f) * 0.015625f - 1.0f;
        }
    }
}

extern "C" void kernel_launch(void* const* d_in, const int* in_sizes, int n_in,
                              void* d_out, int out_size, void* d_ws, size_t ws_size,
                              hipStream_t stream) {
    const float*  verts  = (const float*)d_in[0];
    const int*    faces  = (const int*)d_in[1];
    float*        out    = (float*)d_out;
    unsigned int* packed = (unsigned int*)d_ws;   // 2 MB: 64*8192 uints

    pack_verts_kernel<<<dim3(B_ * NV_ / 256), dim3(256), 0, stream>>>(verts, packed, out);
    mesh_tok_kernel  <<<dim3(B_ * (NF_ / 256)), dim3(256), 0, stream>>>(packed, faces, out);
}